// Round 6
// baseline (181.053 us; speedup 1.0000x reference)
//
#include <hip/hip_runtime.h>

#define KLAB 32
#define FDIM 32
#define NPIX (512 * 512)
#define BATCH 8
#define EPSF 1e-12f

typedef __attribute__((ext_vector_type(8))) short bf16x8;
typedef __attribute__((ext_vector_type(4))) short bf16x4;
typedef __attribute__((ext_vector_type(4))) float f32x4;

__device__ __forceinline__ short f2bf(float f) {
    unsigned u = __builtin_bit_cast(unsigned, f);
    unsigned r = (u + 0x7FFFu + ((u >> 16) & 1u)) >> 16;   // RNE
    return (short)r;
}

__device__ __forceinline__ float bf2f(short s) {
    return __builtin_bit_cast(float, (unsigned)((unsigned short)s) << 16);
}

// Pass 1: per-label sums via MFMA one-hot GEMM, depth-2 load pipeline,
// stash bf16(x) for pass 2. unroll-1 keeps register pressure bounded.
__global__ __launch_bounds__(256) void k_msums(
    const float* __restrict__ x, const int* __restrict__ lab,
    float* __restrict__ g_sums, float* __restrict__ g_cnt,
    short* __restrict__ xbf)
{
    const int tid = threadIdx.x;
    const int b = blockIdx.y;
    const int w = tid >> 6, l = tid & 63;
    const int row = l & 15, grp = l >> 4;
    const int gw = blockIdx.x * 4 + w;              // 0..1023 waves per batch
    const int STEPS = NPIX / 32 / 1024;             // 8
    const size_t xb = (size_t)b * FDIM * NPIX;
    const size_t lb = (size_t)b * NPIX;

    f32x4 acc00{}, acc01{}, acc10{}, acc11{}, accC0{}, accC1{};
    bf16x8 ones;
#pragma unroll
    for (int j = 0; j < 8; ++j) ones[j] = (short)0x3F80;

    const float* xr0 = x + xb + (size_t)row * NPIX;
    const float* xr1 = x + xb + (size_t)(row + 16) * NPIX;
    short* sr0 = xbf + xb + (size_t)row * NPIX;
    short* sr1 = xbf + xb + (size_t)(row + 16) * NPIX;

    // prologue: loads for step 0
    int pg = gw * STEPS * 32 + grp * 8;
    int4 la = *reinterpret_cast<const int4*>(&lab[lb + pg]);
    int4 lc = *reinterpret_cast<const int4*>(&lab[lb + pg + 4]);
    f32x4 v0 = *reinterpret_cast<const f32x4*>(&xr0[pg]);
    f32x4 v1 = *reinterpret_cast<const f32x4*>(&xr0[pg + 4]);
    f32x4 v2 = *reinterpret_cast<const f32x4*>(&xr1[pg]);
    f32x4 v3 = *reinterpret_cast<const f32x4*>(&xr1[pg + 4]);

#pragma unroll 1
    for (int s = 0; s < STEPS; ++s) {
        const int pgn = pg + 32;
        int4 lan{}, lcn{};
        f32x4 w0{}, w1{}, w2{}, w3{};
        if (s + 1 < STEPS) {                         // issue NEXT step's loads first
            lan = *reinterpret_cast<const int4*>(&lab[lb + pgn]);
            lcn = *reinterpret_cast<const int4*>(&lab[lb + pgn + 4]);
            w0 = *reinterpret_cast<const f32x4*>(&xr0[pgn]);
            w1 = *reinterpret_cast<const f32x4*>(&xr0[pgn + 4]);
            w2 = *reinterpret_cast<const f32x4*>(&xr1[pgn]);
            w3 = *reinterpret_cast<const f32x4*>(&xr1[pgn + 4]);
        }

        bf16x8 a0, a1, b0, b1;
        a0[0]=f2bf(v0.x); a0[1]=f2bf(v0.y); a0[2]=f2bf(v0.z); a0[3]=f2bf(v0.w);
        a0[4]=f2bf(v1.x); a0[5]=f2bf(v1.y); a0[6]=f2bf(v1.z); a0[7]=f2bf(v1.w);
        a1[0]=f2bf(v2.x); a1[1]=f2bf(v2.y); a1[2]=f2bf(v2.z); a1[3]=f2bf(v2.w);
        a1[4]=f2bf(v3.x); a1[5]=f2bf(v3.y); a1[6]=f2bf(v3.z); a1[7]=f2bf(v3.w);
        const int lj[8] = {la.x, la.y, la.z, la.w, lc.x, lc.y, lc.z, lc.w};
#pragma unroll
        for (int j = 0; j < 8; ++j) {
            b0[j] = (lj[j] == row)      ? (short)0x3F80 : (short)0;
            b1[j] = (lj[j] == row + 16) ? (short)0x3F80 : (short)0;
        }

        // stash bf16(x) for pass 2
        *reinterpret_cast<bf16x8*>(&sr0[pg]) = a0;
        *reinterpret_cast<bf16x8*>(&sr1[pg]) = a1;

        acc00 = __builtin_amdgcn_mfma_f32_16x16x32_bf16(a0, b0, acc00, 0, 0, 0);
        acc10 = __builtin_amdgcn_mfma_f32_16x16x32_bf16(a1, b0, acc10, 0, 0, 0);
        acc01 = __builtin_amdgcn_mfma_f32_16x16x32_bf16(a0, b1, acc01, 0, 0, 0);
        acc11 = __builtin_amdgcn_mfma_f32_16x16x32_bf16(a1, b1, acc11, 0, 0, 0);
        accC0 = __builtin_amdgcn_mfma_f32_16x16x32_bf16(ones, b0, accC0, 0, 0, 0);
        accC1 = __builtin_amdgcn_mfma_f32_16x16x32_bf16(ones, b1, accC1, 0, 0, 0);

        la = lan; lc = lcn; v0 = w0; v1 = w1; v2 = w2; v3 = w3; pg = pgn;
    }

    __shared__ float s_red[4][FDIM * KLAB];
#pragma unroll
    for (int i = 0; i < 4; ++i) {
        // C layout: col = lane&15, row = (lane>>4)*4 + i  [measured m89]
        const int fr = grp * 4 + i;
        s_red[w][(fr)      * KLAB + row]      = acc00[i];
        s_red[w][(fr)      * KLAB + row + 16] = acc01[i];
        s_red[w][(fr + 16) * KLAB + row]      = acc10[i];
        s_red[w][(fr + 16) * KLAB + row + 16] = acc11[i];
    }
    __syncthreads();
    float* gs = g_sums + (size_t)b * FDIM * KLAB;
    for (int i = tid; i < FDIM * KLAB; i += 256)
        atomicAdd(&gs[i], s_red[0][i] + s_red[1][i] + s_red[2][i] + s_red[3][i]);
    if (l < 16) {   // counts: row 0 of ones-GEMM
        atomicAdd(&g_cnt[b * KLAB + l],      accC0[0]);
        atomicAdd(&g_cnt[b * KLAB + l + 16], accC1[0]);
    }
}

// Pass 2: per-pixel ||mu_label - x|| from the bf16 stash. 4 px/thread,
// depth-4 prefetch (4-slot rotation, full unroll -> static slot indices),
// 8 blocks/CU for ~64 KB outstanding loads per CU.
__global__ __launch_bounds__(256) void k_var(
    const short* __restrict__ xbf, const int* __restrict__ lab,
    const float* __restrict__ g_sums, const float* __restrict__ g_cnt,
    float* __restrict__ g_vsum)
{
    __shared__ float mu_s[FDIM][KLAB];
    __shared__ float vloc[KLAB];
    const int tid = threadIdx.x;
    const int b = blockIdx.y;
    for (int i = tid; i < FDIM * KLAB; i += 256) {
        const int k = i & (KLAB - 1);
        (&mu_s[0][0])[i] = g_sums[(size_t)b * FDIM * KLAB + i] / fmaxf(g_cnt[b * KLAB + k], 1.f);
    }
    if (tid < KLAB) vloc[tid] = 0.f;
    __syncthreads();

    const int n0 = blockIdx.x * 1024 + tid * 4;      // grid(256,B): 4 px/thread
    const size_t lb = (size_t)b * NPIX;
    const int4 l4 = *reinterpret_cast<const int4*>(&lab[lb + n0]);
    const int k0 = l4.x & 31, k1 = l4.y & 31, k2 = l4.z & 31, k3 = l4.w & 31;
    const short* xp = xbf + (size_t)b * FDIM * NPIX + n0;

    bf16x4 sl[4];
#pragma unroll
    for (int f = 0; f < 4; ++f)
        sl[f] = *reinterpret_cast<const bf16x4*>(xp + (size_t)f * NPIX);

    float d0 = 0.f, d1 = 0.f, d2 = 0.f, d3 = 0.f;
#pragma unroll
    for (int f = 0; f < FDIM; ++f) {                 // full unroll: f&3 is static
        const bf16x4 cur = sl[f & 3];
        if (f + 4 < FDIM)
            sl[f & 3] = *reinterpret_cast<const bf16x4*>(xp + (size_t)(f + 4) * NPIX);
        const float* mf = &mu_s[f][0];
        float t;
        t = bf2f(cur[0]) - mf[k0]; d0 += t * t;
        t = bf2f(cur[1]) - mf[k1]; d1 += t * t;
        t = bf2f(cur[2]) - mf[k2]; d2 += t * t;
        t = bf2f(cur[3]) - mf[k3]; d3 += t * t;
    }
    float h;
    h = fmaxf(sqrtf(d0 + EPSF) - 0.5f, 0.f); atomicAdd(&vloc[k0], h * h);
    h = fmaxf(sqrtf(d1 + EPSF) - 0.5f, 0.f); atomicAdd(&vloc[k1], h * h);
    h = fmaxf(sqrtf(d2 + EPSF) - 0.5f, 0.f); atomicAdd(&vloc[k2], h * h);
    h = fmaxf(sqrtf(d3 + EPSF) - 0.5f, 0.f); atomicAdd(&vloc[k3], h * h);
    __syncthreads();
    if (tid < KLAB) atomicAdd(&g_vsum[b * KLAB + tid], vloc[tid]);
}

// Epilogue: all-batch mu staged once in LDS; wave-shuffle reductions; scalar out.
__global__ __launch_bounds__(256) void k_final(
    const float* __restrict__ g_sums, const float* __restrict__ g_cnt,
    const float* __restrict__ g_vsum, float* __restrict__ out)
{
    __shared__ float mu8[BATCH][FDIM][KLAB];   // 32 KB
    __shared__ float cnt8[BATCH][KLAB];
    __shared__ float tot[BATCH];
    const int tid = threadIdx.x;
    const int l = tid & 63, w = tid >> 6;

    for (int i = tid; i < BATCH * FDIM * KLAB; i += 256) {
        const int bb = i >> 10, k = i & 31;
        (&mu8[0][0][0])[i] = g_sums[i] / fmaxf(g_cnt[bb * KLAB + k], 1.f);
    }
    (&cnt8[0][0])[tid] = g_cnt[tid];           // 256 == BATCH*KLAB
    __syncthreads();

    for (int half = 0; half < 2; ++half) {
        const int bb = w + half * 4;           // wave w handles batches w, w+4
        float pres = 0.f, varp = 0.f, regp = 0.f, distp = 0.f;
        if (l < KLAB && cnt8[bb][l] > 0.f) {
            pres = 1.f;
            varp = g_vsum[bb * KLAB + l] / fmaxf(cnt8[bb][l], 1.f);
            float s = 0.f;
            for (int f = 0; f < FDIM; ++f) { float m = mu8[bb][f][l]; s += m * m; }
            regp = sqrtf(s + EPSF);
        }
        for (int p = l; p < KLAB * KLAB; p += 64) {
            const int i = p >> 5, j = p & 31;
            if (i < j && cnt8[bb][i] > 0.f && cnt8[bb][j] > 0.f) {
                float s = 0.f;
                for (int f = 0; f < FDIM; ++f) {
                    float d = mu8[bb][f][i] - mu8[bb][f][j]; s += d * d;
                }
                const float dist = sqrtf(s + EPSF);
                const float hg = fmaxf(1.5f - dist, 0.f);
                distp += hg * hg;
            }
        }
        for (int m = 32; m > 0; m >>= 1) {     // 64-lane butterfly
            pres  += __shfl_xor(pres,  m, 64);
            varp  += __shfl_xor(varp,  m, 64);
            regp  += __shfl_xor(regp,  m, 64);
            distp += __shfl_xor(distp, m, 64);
        }
        if (l == 0) {
            const float C = pres;
            const float var_b = (C > 0.f) ? varp / fmaxf(C, 1.f) : 0.f;
            const float dis_b = (C > 2.f) ? distp / fmaxf(C * (C - 1.f), 1.f) : 0.f;
            const float reg_b = (C > 1.f) ? regp : 0.f;
            tot[bb] = var_b + dis_b + 0.001f * reg_b;
        }
    }
    __syncthreads();
    if (tid == 0) {
        float t = 0.f;
        for (int bb = 0; bb < BATCH; ++bb) t += tot[bb];
        out[0] = t;
    }
}

extern "C" void kernel_launch(void* const* d_in, const int* in_sizes, int n_in,
                              void* d_out, int out_size, void* d_ws, size_t ws_size,
                              hipStream_t stream) {
    const float* x = (const float*)d_in[0];
    const int* lab = (const int*)d_in[1];
    float* out = (float*)d_out;

    // ws: xbf [B][F][N] bf16 (128 MiB) | sums [B][F][K] | counts [B][K] | vsums [B][K]
    const size_t XBF_BYTES = (size_t)BATCH * FDIM * NPIX * 2;
    short* xbf    = (short*)d_ws;
    float* g_sums = (float*)((char*)d_ws + XBF_BYTES);
    float* g_cnt  = g_sums + (size_t)BATCH * FDIM * KLAB;
    float* g_vsum = g_cnt + (size_t)BATCH * KLAB;
    hipMemsetAsync(g_sums, 0, (size_t)(BATCH * FDIM * KLAB + 2 * BATCH * KLAB) * 4, stream);

    dim3 grid1(256, BATCH);    // 1024 waves/batch, 8 pipelined MFMA steps each
    k_msums<<<grid1, 256, 0, stream>>>(x, lab, g_sums, g_cnt, xbf);
    dim3 grid2(256, BATCH);    // 1024 px/block, 4 px/thread, 8 blocks/CU
    k_var<<<grid2, 256, 0, stream>>>(xbf, lab, g_sums, g_cnt, g_vsum);
    k_final<<<1, 256, 0, stream>>>(g_sums, g_cnt, g_vsum, out);
}

// Round 7
// 148.673 us; speedup vs baseline: 1.2178x; 1.2178x over previous
//
#include <hip/hip_runtime.h>

#define KLAB 32
#define FDIM 32
#define NPIX (512 * 512)
#define BATCH 8
#define EPSF 1e-12f

typedef __attribute__((ext_vector_type(8))) short bf16x8;
typedef __attribute__((ext_vector_type(4))) short bf16x4;
typedef __attribute__((ext_vector_type(4))) float f32x4;

__device__ __forceinline__ short f2bf(float f) {
    unsigned u = __builtin_bit_cast(unsigned, f);
    unsigned r = (u + 0x7FFFu + ((u >> 16) & 1u)) >> 16;   // RNE
    return (short)r;
}

__device__ __forceinline__ float bf2f(short s) {
    return __builtin_bit_cast(float, (unsigned)((unsigned short)s) << 16);
}

// Pass 1: LDS-staged MFMA one-hot GEMM.
// Per block: 2048 px as 8 tiles x 256 px. Stage: coalesced 1KB-per-instr row
// loads (issue-early), convert once, stash bf16 to global + XOR-swizzled LDS
// (write-late). Compute: MFMA fragments from LDS. Double-buffered.
__global__ __launch_bounds__(256, 4) void k_msums(
    const float* __restrict__ x, const int* __restrict__ lab,
    float* __restrict__ g_sums, float* __restrict__ g_cnt,
    short* __restrict__ xbf)
{
    __shared__ __align__(16) short alds[2][32 * 256];   // 2 x 16 KB bf16 tile
    __shared__ int lablds[2][256];

    const int tid = threadIdx.x;
    const int b = blockIdx.y;
    const int cx = blockIdx.x;                 // 0..127
    const int w = tid >> 6, l = tid & 63;
    const int row = l & 15, grp = l >> 4;
    const size_t xb = (size_t)b * FDIM * NPIX;
    const size_t lb = (size_t)b * NPIX;
    const int bp0 = cx * 2048;

    const float* xw = x + xb + (size_t)(w * 8) * NPIX;   // wave's 8 staging rows
    short* xbw = xbf + xb + (size_t)(w * 8) * NPIX;

    f32x4 acc00{}, acc01{}, acc10{}, acc11{}, accC0{}, accC1{};
    bf16x8 ones;
#pragma unroll
    for (int j = 0; j < 8; ++j) ones[j] = (short)0x3F80;

    f32x4 sv[8];                               // staged rows (static idx via unroll)
    int slab;

    // ---- prologue: stage tile 0 into buf 0 ----
    {
        const int sp = bp0;
#pragma unroll
        for (int r = 0; r < 8; ++r)
            sv[r] = *reinterpret_cast<const f32x4*>(xw + (size_t)r * NPIX + sp + l * 4);
        slab = lab[lb + sp + tid];
#pragma unroll
        for (int r = 0; r < 8; ++r) {
            bf16x4 c;
            c[0]=f2bf(sv[r].x); c[1]=f2bf(sv[r].y); c[2]=f2bf(sv[r].z); c[3]=f2bf(sv[r].w);
            *reinterpret_cast<bf16x4*>(xbw + (size_t)r * NPIX + sp + l * 4) = c;
            const int f = w * 8 + r;           // f&7 == r
            *reinterpret_cast<bf16x4*>((char*)&alds[0][0] + ((f * 512 + l * 8) ^ (r << 4))) = c;
        }
        lablds[0][tid] = slab;
    }
    __syncthreads();

#pragma unroll 1
    for (int t = 0; t < 8; ++t) {
        const int cb = t & 1, nb = cb ^ 1;

        // issue-early: next tile's coalesced loads (hide HBM under compute)
        if (t + 1 < 8) {
            const int sp = bp0 + (t + 1) * 256;
#pragma unroll
            for (int r = 0; r < 8; ++r)
                sv[r] = *reinterpret_cast<const f32x4*>(xw + (size_t)r * NPIX + sp + l * 4);
            slab = lab[lb + sp + tid];
        }

        // compute current tile: this wave owns k-steps 2w, 2w+1 (32 px each)
#pragma unroll
        for (int kq = 0; kq < 2; ++kq) {
            const int kk = 2 * w + kq;
            const int cbyte = (kk * 32 + grp * 8) * 2;
            const int swz = (row & 7) << 4;    // (row+16)&7 == row&7
            const bf16x8 a0 = *reinterpret_cast<const bf16x8*>(
                (char*)&alds[cb][0] + ((row * 512 + cbyte) ^ swz));
            const bf16x8 a1 = *reinterpret_cast<const bf16x8*>(
                (char*)&alds[cb][0] + (((row + 16) * 512 + cbyte) ^ swz));
            const int base = kk * 32 + grp * 8;
            const int4 la = *reinterpret_cast<const int4*>(&lablds[cb][base]);
            const int4 lc = *reinterpret_cast<const int4*>(&lablds[cb][base + 4]);
            bf16x8 b0, b1;
            const int lj[8] = {la.x, la.y, la.z, la.w, lc.x, lc.y, lc.z, lc.w};
#pragma unroll
            for (int j = 0; j < 8; ++j) {
                b0[j] = (lj[j] == row)      ? (short)0x3F80 : (short)0;
                b1[j] = (lj[j] == row + 16) ? (short)0x3F80 : (short)0;
            }
            acc00 = __builtin_amdgcn_mfma_f32_16x16x32_bf16(a0, b0, acc00, 0, 0, 0);
            acc10 = __builtin_amdgcn_mfma_f32_16x16x32_bf16(a1, b0, acc10, 0, 0, 0);
            acc01 = __builtin_amdgcn_mfma_f32_16x16x32_bf16(a0, b1, acc01, 0, 0, 0);
            acc11 = __builtin_amdgcn_mfma_f32_16x16x32_bf16(a1, b1, acc11, 0, 0, 0);
            accC0 = __builtin_amdgcn_mfma_f32_16x16x32_bf16(ones, b0, accC0, 0, 0, 0);
            accC1 = __builtin_amdgcn_mfma_f32_16x16x32_bf16(ones, b1, accC1, 0, 0, 0);
        }

        // write-late: convert + stash (global, coalesced) + LDS next buffer
        if (t + 1 < 8) {
            const int sp = bp0 + (t + 1) * 256;
#pragma unroll
            for (int r = 0; r < 8; ++r) {
                bf16x4 c;
                c[0]=f2bf(sv[r].x); c[1]=f2bf(sv[r].y); c[2]=f2bf(sv[r].z); c[3]=f2bf(sv[r].w);
                *reinterpret_cast<bf16x4*>(xbw + (size_t)r * NPIX + sp + l * 4) = c;
                const int f = w * 8 + r;
                *reinterpret_cast<bf16x4*>((char*)&alds[nb][0] + ((f * 512 + l * 8) ^ (r << 4))) = c;
            }
            lablds[nb][tid] = slab;
        }
        __syncthreads();
    }

    // epilogue: block reduce (s_red aliases alds[0]; last compute used buf 1)
    float* s_red = reinterpret_cast<float*>(&alds[0][0]);   // [4][1024]
#pragma unroll
    for (int i = 0; i < 4; ++i) {
        // C layout: col = lane&15, row = (lane>>4)*4 + i  [measured m89]
        const int fr = grp * 4 + i;
        s_red[w * 1024 + (fr)      * KLAB + row]      = acc00[i];
        s_red[w * 1024 + (fr)      * KLAB + row + 16] = acc01[i];
        s_red[w * 1024 + (fr + 16) * KLAB + row]      = acc10[i];
        s_red[w * 1024 + (fr + 16) * KLAB + row + 16] = acc11[i];
    }
    __syncthreads();
    float* gs = g_sums + (size_t)b * FDIM * KLAB;
    for (int i = tid; i < FDIM * KLAB; i += 256)
        atomicAdd(&gs[i], s_red[i] + s_red[1024 + i] + s_red[2048 + i] + s_red[3072 + i]);
    if (l < 16) {   // counts: row 0 of ones-GEMM
        atomicAdd(&g_cnt[b * KLAB + l],      accC0[0]);
        atomicAdd(&g_cnt[b * KLAB + l + 16], accC1[0]);
    }
}

// Pass 2: per-pixel ||mu_label - x|| from the bf16 stash. 4 px/thread,
// depth-4 prefetch (static slot indices), 8 blocks/CU.
__global__ __launch_bounds__(256) void k_var(
    const short* __restrict__ xbf, const int* __restrict__ lab,
    const float* __restrict__ g_sums, const float* __restrict__ g_cnt,
    float* __restrict__ g_vsum)
{
    __shared__ float mu_s[FDIM][KLAB];
    __shared__ float vloc[KLAB];
    const int tid = threadIdx.x;
    const int b = blockIdx.y;
    for (int i = tid; i < FDIM * KLAB; i += 256) {
        const int k = i & (KLAB - 1);
        (&mu_s[0][0])[i] = g_sums[(size_t)b * FDIM * KLAB + i] / fmaxf(g_cnt[b * KLAB + k], 1.f);
    }
    if (tid < KLAB) vloc[tid] = 0.f;
    __syncthreads();

    const int n0 = blockIdx.x * 1024 + tid * 4;      // grid(256,B): 4 px/thread
    const size_t lb = (size_t)b * NPIX;
    const int4 l4 = *reinterpret_cast<const int4*>(&lab[lb + n0]);
    const int k0 = l4.x & 31, k1 = l4.y & 31, k2 = l4.z & 31, k3 = l4.w & 31;
    const short* xp = xbf + (size_t)b * FDIM * NPIX + n0;

    bf16x4 sl[4];
#pragma unroll
    for (int f = 0; f < 4; ++f)
        sl[f] = *reinterpret_cast<const bf16x4*>(xp + (size_t)f * NPIX);

    float d0 = 0.f, d1 = 0.f, d2 = 0.f, d3 = 0.f;
#pragma unroll
    for (int f = 0; f < FDIM; ++f) {                 // full unroll: f&3 static
        const bf16x4 cur = sl[f & 3];
        if (f + 4 < FDIM)
            sl[f & 3] = *reinterpret_cast<const bf16x4*>(xp + (size_t)(f + 4) * NPIX);
        const float* mf = &mu_s[f][0];
        float t;
        t = bf2f(cur[0]) - mf[k0]; d0 += t * t;
        t = bf2f(cur[1]) - mf[k1]; d1 += t * t;
        t = bf2f(cur[2]) - mf[k2]; d2 += t * t;
        t = bf2f(cur[3]) - mf[k3]; d3 += t * t;
    }
    float h;
    h = fmaxf(sqrtf(d0 + EPSF) - 0.5f, 0.f); atomicAdd(&vloc[k0], h * h);
    h = fmaxf(sqrtf(d1 + EPSF) - 0.5f, 0.f); atomicAdd(&vloc[k1], h * h);
    h = fmaxf(sqrtf(d2 + EPSF) - 0.5f, 0.f); atomicAdd(&vloc[k2], h * h);
    h = fmaxf(sqrtf(d3 + EPSF) - 0.5f, 0.f); atomicAdd(&vloc[k3], h * h);
    __syncthreads();
    if (tid < KLAB) atomicAdd(&g_vsum[b * KLAB + tid], vloc[tid]);
}

// Epilogue: all-batch mu staged once in LDS; wave-shuffle reductions; scalar out.
__global__ __launch_bounds__(256) void k_final(
    const float* __restrict__ g_sums, const float* __restrict__ g_cnt,
    const float* __restrict__ g_vsum, float* __restrict__ out)
{
    __shared__ float mu8[BATCH][FDIM][KLAB];   // 32 KB
    __shared__ float cnt8[BATCH][KLAB];
    __shared__ float tot[BATCH];
    const int tid = threadIdx.x;
    const int l = tid & 63, w = tid >> 6;

    for (int i = tid; i < BATCH * FDIM * KLAB; i += 256) {
        const int bb = i >> 10, k = i & 31;
        (&mu8[0][0][0])[i] = g_sums[i] / fmaxf(g_cnt[bb * KLAB + k], 1.f);
    }
    (&cnt8[0][0])[tid] = g_cnt[tid];           // 256 == BATCH*KLAB
    __syncthreads();

    for (int half = 0; half < 2; ++half) {
        const int bb = w + half * 4;           // wave w handles batches w, w+4
        float pres = 0.f, varp = 0.f, regp = 0.f, distp = 0.f;
        if (l < KLAB && cnt8[bb][l] > 0.f) {
            pres = 1.f;
            varp = g_vsum[bb * KLAB + l] / fmaxf(cnt8[bb][l], 1.f);
            float s = 0.f;
            for (int f = 0; f < FDIM; ++f) { float m = mu8[bb][f][l]; s += m * m; }
            regp = sqrtf(s + EPSF);
        }
        for (int p = l; p < KLAB * KLAB; p += 64) {
            const int i = p >> 5, j = p & 31;
            if (i < j && cnt8[bb][i] > 0.f && cnt8[bb][j] > 0.f) {
                float s = 0.f;
                for (int f = 0; f < FDIM; ++f) {
                    float d = mu8[bb][f][i] - mu8[bb][f][j]; s += d * d;
                }
                const float dist = sqrtf(s + EPSF);
                const float hg = fmaxf(1.5f - dist, 0.f);
                distp += hg * hg;
            }
        }
        for (int m = 32; m > 0; m >>= 1) {     // 64-lane butterfly
            pres  += __shfl_xor(pres,  m, 64);
            varp  += __shfl_xor(varp,  m, 64);
            regp  += __shfl_xor(regp,  m, 64);
            distp += __shfl_xor(distp, m, 64);
        }
        if (l == 0) {
            const float C = pres;
            const float var_b = (C > 0.f) ? varp / fmaxf(C, 1.f) : 0.f;
            const float dis_b = (C > 2.f) ? distp / fmaxf(C * (C - 1.f), 1.f) : 0.f;
            const float reg_b = (C > 1.f) ? regp : 0.f;
            tot[bb] = var_b + dis_b + 0.001f * reg_b;
        }
    }
    __syncthreads();
    if (tid == 0) {
        float t = 0.f;
        for (int bb = 0; bb < BATCH; ++bb) t += tot[bb];
        out[0] = t;
    }
}

extern "C" void kernel_launch(void* const* d_in, const int* in_sizes, int n_in,
                              void* d_out, int out_size, void* d_ws, size_t ws_size,
                              hipStream_t stream) {
    const float* x = (const float*)d_in[0];
    const int* lab = (const int*)d_in[1];
    float* out = (float*)d_out;

    // ws: xbf [B][F][N] bf16 (128 MiB) | sums [B][F][K] | counts [B][K] | vsums [B][K]
    const size_t XBF_BYTES = (size_t)BATCH * FDIM * NPIX * 2;
    short* xbf    = (short*)d_ws;
    float* g_sums = (float*)((char*)d_ws + XBF_BYTES);
    float* g_cnt  = g_sums + (size_t)BATCH * FDIM * KLAB;
    float* g_vsum = g_cnt + (size_t)BATCH * KLAB;
    hipMemsetAsync(g_sums, 0, (size_t)(BATCH * FDIM * KLAB + 2 * BATCH * KLAB) * 4, stream);

    dim3 grid1(128, BATCH);    // 1024 blocks = exactly 4/CU co-resident
    k_msums<<<grid1, 256, 0, stream>>>(x, lab, g_sums, g_cnt, xbf);
    dim3 grid2(256, BATCH);    // 1024 px/block, 4 px/thread, 8 blocks/CU
    k_var<<<grid2, 256, 0, stream>>>(xbf, lab, g_sums, g_cnt, g_vsum);
    k_final<<<1, 256, 0, stream>>>(g_sums, g_cnt, g_vsum, out);
}